// Round 5
// baseline (68.873 us; speedup 1.0000x reference)
//
#include <hip/hip_runtime.h>
#include <math.h>

constexpr int Bdim = 32;
constexpr int Mdim = 8192;
constexpr int Idim = 256;
constexpr int ROWS_PER_BLOCK = 128;               // 4 waves x 32 rows
constexpr int ROWS_PER_WAVE = 32;                 // processed as 16 pairs
constexpr int NCHUNK = Mdim / ROWS_PER_BLOCK;     // 64 chunks per b
constexpr int NSLICE = 8;                         // epilogue parallelism per b

typedef float vfloat4 __attribute__((ext_vector_type(4)));  // native vec for nt loads

// ---------------------------------------------------------------------------
// 1) projected_key[b,i] = tanh(sum_k key[b,k] * W[i,k] + bias[i])
// ---------------------------------------------------------------------------
__global__ void proj_key_kernel(const float* __restrict__ key,
                                const float* __restrict__ W,
                                const float* __restrict__ bias,
                                float* __restrict__ pk) {
    int b = blockIdx.x;
    int i = threadIdx.x;
    __shared__ float kq[Idim];
    kq[i] = key[b * Idim + i];
    __syncthreads();
    const float4* w4 = (const float4*)(W + (size_t)i * Idim);
    const float4* k4 = (const float4*)kq;
    float s = bias[i];
    #pragma unroll 4
    for (int k = 0; k < Idim / 4; ++k) {
        float4 wv = w4[k];
        float4 kv = k4[k];
        s += wv.x * kv.x + wv.y * kv.y + wv.z * kv.z + wv.w * kv.w;
    }
    pk[b * Idim + i] = tanhf(s);
}

// ---------------------------------------------------------------------------
// 2) FUSED single pass over memory. Half-wave per row; nontemporal loads
//    for the read-once 256 MiB stream. Online softmax, guarded rescale.
// ---------------------------------------------------------------------------
__global__ void fused_pass1_kernel(const float* __restrict__ memory,
                                   const float* __restrict__ pk,
                                   const float* __restrict__ beta,
                                   float* __restrict__ sim,
                                   float* __restrict__ pvec,
                                   float* __restrict__ pmx,
                                   float* __restrict__ psum) {
    int b = blockIdx.x / NCHUNK;
    int c = blockIdx.x % NCHUNK;
    int wave = threadIdx.x >> 6;
    int lane = threadIdx.x & 63;
    int half = lane >> 5;                       // which row of the pair
    int sub  = lane & 31;                       // position within the row
    float bt = beta[b];

    // this lane's 8 projected-key elements [sub*8, sub*8+8)
    const float4* pk4 = (const float4*)(pk + b * Idim);
    float4 pk0 = pk4[sub * 2];
    float4 pk1 = pk4[sub * 2 + 1];

    int row0 = c * ROWS_PER_BLOCK + wave * ROWS_PER_WAVE;
    const float* base = memory + ((size_t)b * Mdim + row0) * Idim;
    float* simp = sim + (size_t)b * Mdim + row0;

    float mx = -INFINITY, ssum = 0.f;
    float4 acc0 = make_float4(0.f, 0.f, 0.f, 0.f);
    float4 acc1 = make_float4(0.f, 0.f, 0.f, 0.f);
    float my_sim = 0.f;                         // lane w<32 keeps sim of row w

    #pragma unroll
    for (int t = 0; t < ROWS_PER_WAVE / 2; ++t) {
        const vfloat4* rp = (const vfloat4*)(base + (size_t)(2 * t + half) * Idim + sub * 8);
        vfloat4 m0 = __builtin_nontemporal_load(rp);
        vfloat4 m1 = __builtin_nontemporal_load(rp + 1);

        float d, s;
        d = pk0.x - m0.x; s  = d * d;
        d = pk0.y - m0.y; s += d * d;
        d = pk0.z - m0.z; s += d * d;
        d = pk0.w - m0.w; s += d * d;
        d = pk1.x - m1.x; s += d * d;
        d = pk1.y - m1.y; s += d * d;
        d = pk1.z - m1.z; s += d * d;
        d = pk1.w - m1.w; s += d * d;
        #pragma unroll
        for (int off = 16; off; off >>= 1) s += __shfl_xor(s, off, 64);
        // all lanes of a half now hold their row's full distance
        float s_other = __shfl_xor(s, 32, 64);
        if ((lane >> 1) == t) my_sim = (lane & 1) ? -s_other : -s;

        float a = -bt * s;
        if (a > mx) {                           // rare after first few rows
            float scale = __expf(mx - a);       // exp(-inf)=0 handles t=0
            ssum *= scale;
            acc0.x *= scale; acc0.y *= scale; acc0.z *= scale; acc0.w *= scale;
            acc1.x *= scale; acc1.y *= scale; acc1.z *= scale; acc1.w *= scale;
            mx = a;
        }
        float p = __expf(a - mx);
        ssum += p;
        acc0.x = fmaf(p, m0.x, acc0.x);
        acc0.y = fmaf(p, m0.y, acc0.y);
        acc0.z = fmaf(p, m0.z, acc0.z);
        acc0.w = fmaf(p, m0.w, acc0.w);
        acc1.x = fmaf(p, m1.x, acc1.x);
        acc1.y = fmaf(p, m1.y, acc1.y);
        acc1.z = fmaf(p, m1.z, acc1.z);
        acc1.w = fmaf(p, m1.w, acc1.w);
    }
    if (lane < 32) simp[lane] = my_sim;         // coalesced 32-row sim store

    // combine the block's 8 wave-halves in LDS
    __shared__ float lacc[8][Idim];
    __shared__ float lmx[8], lsum[8];
    int wh = wave * 2 + half;
    ((float4*)(lacc[wh] + sub * 8))[0] = acc0;
    ((float4*)(lacc[wh] + sub * 8))[1] = acc1;
    if (sub == 0) { lmx[wh] = mx; lsum[wh] = ssum; }
    __syncthreads();

    float MX = lmx[0];
    #pragma unroll
    for (int h = 1; h < 8; ++h) MX = fmaxf(MX, lmx[h]);
    float e[8];
    #pragma unroll
    for (int h = 0; h < 8; ++h) e[h] = __expf(lmx[h] - MX);

    int i = threadIdx.x;
    float v = 0.f;
    #pragma unroll
    for (int h = 0; h < 8; ++h) v += lacc[h][i] * e[h];
    size_t pc = (size_t)b * NCHUNK + c;
    pvec[pc * Idim + i] = v;
    if (threadIdx.x == 0) {
        float sc = 0.f;
        #pragma unroll
        for (int h = 0; h < 8; ++h) sc += lsum[h] * e[h];
        pmx[pc] = MX;
        psum[pc] = sc;
    }
}

// ---------------------------------------------------------------------------
// 3) Epilogue, grid = B * NSLICE blocks. Every block redundantly reduces the
//    64 chunk (mx,sum) pairs for its b (cheap); slice 0 emits read_vector;
//    each slice emits Mdim/NSLICE weights (one float4 per thread).
// ---------------------------------------------------------------------------
__global__ void epilogue_kernel(const float* __restrict__ pvec,
                                const float* __restrict__ pmx,
                                const float* __restrict__ psum,
                                const float* __restrict__ sim,
                                const float* __restrict__ beta,
                                float* __restrict__ read_vec,
                                float* __restrict__ weights) {
    int b = blockIdx.x / NSLICE;
    int slice = blockIdx.x % NSLICE;
    int tid = threadIdx.x;
    __shared__ float e[NCHUNK];
    __shared__ float MXs, sInvs;

    if (tid < NCHUNK) {                         // wave 0 handles the scalars
        float m = pmx[(size_t)b * NCHUNK + tid];
        float mm = m;
        #pragma unroll
        for (int off = 32; off; off >>= 1) mm = fmaxf(mm, __shfl_xor(mm, off, 64));
        float ec = __expf(m - mm);
        e[tid] = ec;
        float sc = psum[(size_t)b * NCHUNK + tid] * ec;
        #pragma unroll
        for (int off = 32; off; off >>= 1) sc += __shfl_xor(sc, off, 64);
        if (tid == 0) { MXs = mm; sInvs = 1.f / sc; }
    }
    __syncthreads();

    float MX = MXs, inv = sInvs;

    if (slice == 0) {                           // read_vector
        float v = 0.f;
        const float* p = pvec + (size_t)b * NCHUNK * Idim + tid;
        #pragma unroll 8
        for (int c = 0; c < NCHUNK; ++c) v += p[(size_t)c * Idim] * e[c];
        read_vec[(size_t)b * Idim + tid] = v * inv;
    }

    // weights: this slice covers Mdim/NSLICE = 1024 elems = 256 float4s
    float bt = beta[b];
    int m4 = slice * (Mdim / NSLICE / 4) + tid;
    float4 s = ((const float4*)(sim + (size_t)b * Mdim))[m4];
    float4 w;
    w.x = __expf(bt * s.x - MX) * inv;
    w.y = __expf(bt * s.y - MX) * inv;
    w.z = __expf(bt * s.z - MX) * inv;
    w.w = __expf(bt * s.w - MX) * inv;
    ((float4*)(weights + (size_t)b * Mdim))[m4] = w;
}

extern "C" void kernel_launch(void* const* d_in, const int* in_sizes, int n_in,
                              void* d_out, int out_size, void* d_ws, size_t ws_size,
                              hipStream_t stream) {
    const float* memory = (const float*)d_in[0];   // [B, M, I]
    const float* key    = (const float*)d_in[1];   // [B, I]
    const float* beta   = (const float*)d_in[2];   // [B]
    const float* W      = (const float*)d_in[3];   // [I, I]
    const float* bias   = (const float*)d_in[4];   // [I]

    float* out = (float*)d_out;
    float* weights  = out;                                     // [B, M]
    float* read_vec = out + (size_t)Bdim * Mdim;               // [B, I]
    float* sim      = read_vec + (size_t)Bdim * Idim;          // [B, M]

    float* pk   = (float*)d_ws;                                // [B, I]
    float* pvec = pk + (size_t)Bdim * Idim;                    // [B, NCHUNK, I]
    float* pmx  = pvec + (size_t)Bdim * NCHUNK * Idim;         // [B, NCHUNK]
    float* psum = pmx + (size_t)Bdim * NCHUNK;                 // [B, NCHUNK]

    proj_key_kernel<<<Bdim, Idim, 0, stream>>>(key, W, bias, pk);
    fused_pass1_kernel<<<Bdim * NCHUNK, 256, 0, stream>>>(memory, pk, beta,
                                                          sim, pvec, pmx, psum);
    epilogue_kernel<<<Bdim * NSLICE, 256, 0, stream>>>(pvec, pmx, psum, sim, beta,
                                                       read_vec, weights);
}

// Round 6
// 62.354 us; speedup vs baseline: 1.1046x; 1.1046x over previous
//
#include <hip/hip_runtime.h>
#include <math.h>

constexpr int Bdim = 32;
constexpr int Mdim = 8192;
constexpr int Idim = 256;
constexpr int ROWS_PER_BLOCK = 128;               // 4 waves x 32 rows
constexpr int ROWS_PER_WAVE = 32;
constexpr int NCHUNK = Mdim / ROWS_PER_BLOCK;     // 64 chunks per b
constexpr int NSLICE = 8;                         // epilogue parallelism per b

// ---------------------------------------------------------------------------
// 1) projected_key[b,i] = tanh(sum_k key[b,k] * W[i,k] + bias[i])
// ---------------------------------------------------------------------------
__global__ void proj_key_kernel(const float* __restrict__ key,
                                const float* __restrict__ W,
                                const float* __restrict__ bias,
                                float* __restrict__ pk) {
    int b = blockIdx.x;
    int i = threadIdx.x;
    __shared__ float kq[Idim];
    kq[i] = key[b * Idim + i];
    __syncthreads();
    const float4* w4 = (const float4*)(W + (size_t)i * Idim);
    const float4* k4 = (const float4*)kq;
    float s = bias[i];
    #pragma unroll 4
    for (int k = 0; k < Idim / 4; ++k) {
        float4 wv = w4[k];
        float4 kv = k4[k];
        s += wv.x * kv.x + wv.y * kv.y + wv.z * kv.z + wv.w * kv.w;
    }
    pk[b * Idim + i] = tanhf(s);
}

// ---------------------------------------------------------------------------
// 2) FUSED single pass over memory (R2 structure + 2-deep prefetch).
//    One wave per row: 64 lanes x float4 = 1 KiB coalesced; 32 rows/wave.
//    Online softmax, wave-uniform guarded rescale. Plain (cached) loads.
// ---------------------------------------------------------------------------
__global__ void fused_pass1_kernel(const float* __restrict__ memory,
                                   const float* __restrict__ pk,
                                   const float* __restrict__ beta,
                                   float* __restrict__ sim,
                                   float* __restrict__ pvec,
                                   float* __restrict__ pmx,
                                   float* __restrict__ psum) {
    int b = blockIdx.x / NCHUNK;
    int c = blockIdx.x % NCHUNK;
    int wave = threadIdx.x >> 6;
    int lane = threadIdx.x & 63;
    float bt = beta[b];

    float4 pkv = ((const float4*)(pk + b * Idim))[lane];

    int row0 = c * ROWS_PER_BLOCK + wave * ROWS_PER_WAVE;
    const float* base = memory + ((size_t)b * Mdim + row0) * Idim;
    float* simp = sim + (size_t)b * Mdim + row0;

    float mx = -INFINITY, ssum = 0.f;
    float4 acc = make_float4(0.f, 0.f, 0.f, 0.f);
    float my_sim = 0.f;                         // lane r (<32) keeps sim of row r

    auto body = [&](float4 mv, int r) {
        float dx = pkv.x - mv.x, dy = pkv.y - mv.y;
        float dz = pkv.z - mv.z, dw = pkv.w - mv.w;
        float s = dx * dx + dy * dy + dz * dz + dw * dw;
        #pragma unroll
        for (int off = 32; off; off >>= 1) s += __shfl_xor(s, off, 64);
        if (lane == r) my_sim = -s;             // all 64 lanes hold full distance
        float a = -bt * s;
        if (a > mx) {                           // wave-uniform, rare after warmup
            float sc = __expf(mx - a);          // exp(-inf)=0 handles r=0
            ssum *= sc;
            acc.x *= sc; acc.y *= sc; acc.z *= sc; acc.w *= sc;
            mx = a;
        }
        float p = __expf(a - mx);
        ssum += p;
        acc.x = fmaf(p, mv.x, acc.x);
        acc.y = fmaf(p, mv.y, acc.y);
        acc.z = fmaf(p, mv.z, acc.z);
        acc.w = fmaf(p, mv.w, acc.w);
    };

    // row stride in float4s = Idim/4 = 64; lane covers float4 #lane of each row
    const float4* rp = (const float4*)base + lane;
    float4 cur = rp[0];
    float4 nxt = rp[64];
    #pragma unroll 2
    for (int r = 0; r < ROWS_PER_WAVE - 2; ++r) {
        float4 pf = rp[(size_t)(r + 2) * 64];   // issue prefetch before compute
        body(cur, r);
        cur = nxt;
        nxt = pf;
    }
    body(cur, ROWS_PER_WAVE - 2);
    body(nxt, ROWS_PER_WAVE - 1);

    if (lane < 32) simp[lane] = my_sim;         // coalesced 32-row sim store

    // combine the block's 4 waves in LDS
    __shared__ float lacc[4][Idim];
    __shared__ float lmx[4], lsum[4];
    ((float4*)lacc[wave])[lane] = acc;
    if (lane == 0) { lmx[wave] = mx; lsum[wave] = ssum; }
    __syncthreads();

    float MX = fmaxf(fmaxf(lmx[0], lmx[1]), fmaxf(lmx[2], lmx[3]));
    float e0 = __expf(lmx[0] - MX), e1 = __expf(lmx[1] - MX);
    float e2 = __expf(lmx[2] - MX), e3 = __expf(lmx[3] - MX);
    int i = threadIdx.x;
    float v = lacc[0][i] * e0 + lacc[1][i] * e1 + lacc[2][i] * e2 + lacc[3][i] * e3;
    size_t pc = (size_t)b * NCHUNK + c;
    pvec[pc * Idim + i] = v;
    if (threadIdx.x == 0) {
        pmx[pc] = MX;
        psum[pc] = lsum[0] * e0 + lsum[1] * e1 + lsum[2] * e2 + lsum[3] * e3;
    }
}

// ---------------------------------------------------------------------------
// 3) Epilogue, grid = B * NSLICE blocks. Every block redundantly reduces the
//    64 chunk (mx,sum) pairs for its b (cheap); slice 0 emits read_vector;
//    each slice emits Mdim/NSLICE weights (one float4 per thread).
// ---------------------------------------------------------------------------
__global__ void epilogue_kernel(const float* __restrict__ pvec,
                                const float* __restrict__ pmx,
                                const float* __restrict__ psum,
                                const float* __restrict__ sim,
                                const float* __restrict__ beta,
                                float* __restrict__ read_vec,
                                float* __restrict__ weights) {
    int b = blockIdx.x / NSLICE;
    int slice = blockIdx.x % NSLICE;
    int tid = threadIdx.x;
    __shared__ float e[NCHUNK];
    __shared__ float MXs, sInvs;

    if (tid < NCHUNK) {                         // wave 0 handles the scalars
        float m = pmx[(size_t)b * NCHUNK + tid];
        float mm = m;
        #pragma unroll
        for (int off = 32; off; off >>= 1) mm = fmaxf(mm, __shfl_xor(mm, off, 64));
        float ec = __expf(m - mm);
        e[tid] = ec;
        float sc = psum[(size_t)b * NCHUNK + tid] * ec;
        #pragma unroll
        for (int off = 32; off; off >>= 1) sc += __shfl_xor(sc, off, 64);
        if (tid == 0) { MXs = mm; sInvs = 1.f / sc; }
    }
    __syncthreads();

    float MX = MXs, inv = sInvs;

    if (slice == 0) {                           // read_vector
        float v = 0.f;
        const float* p = pvec + (size_t)b * NCHUNK * Idim + tid;
        #pragma unroll 8
        for (int c = 0; c < NCHUNK; ++c) v += p[(size_t)c * Idim] * e[c];
        read_vec[(size_t)b * Idim + tid] = v * inv;
    }

    // weights: this slice covers Mdim/NSLICE = 1024 elems = 256 float4s
    float bt = beta[b];
    int m4 = slice * (Mdim / NSLICE / 4) + tid;
    float4 s = ((const float4*)(sim + (size_t)b * Mdim))[m4];
    float4 w;
    w.x = __expf(bt * s.x - MX) * inv;
    w.y = __expf(bt * s.y - MX) * inv;
    w.z = __expf(bt * s.z - MX) * inv;
    w.w = __expf(bt * s.w - MX) * inv;
    ((float4*)(weights + (size_t)b * Mdim))[m4] = w;
}

extern "C" void kernel_launch(void* const* d_in, const int* in_sizes, int n_in,
                              void* d_out, int out_size, void* d_ws, size_t ws_size,
                              hipStream_t stream) {
    const float* memory = (const float*)d_in[0];   // [B, M, I]
    const float* key    = (const float*)d_in[1];   // [B, I]
    const float* beta   = (const float*)d_in[2];   // [B]
    const float* W      = (const float*)d_in[3];   // [I, I]
    const float* bias   = (const float*)d_in[4];   // [I]

    float* out = (float*)d_out;
    float* weights  = out;                                     // [B, M]
    float* read_vec = out + (size_t)Bdim * Mdim;               // [B, I]
    float* sim      = read_vec + (size_t)Bdim * Idim;          // [B, M]

    float* pk   = (float*)d_ws;                                // [B, I]
    float* pvec = pk + (size_t)Bdim * Idim;                    // [B, NCHUNK, I]
    float* pmx  = pvec + (size_t)Bdim * NCHUNK * Idim;         // [B, NCHUNK]
    float* psum = pmx + (size_t)Bdim * NCHUNK;                 // [B, NCHUNK]

    proj_key_kernel<<<Bdim, Idim, 0, stream>>>(key, W, bias, pk);
    fused_pass1_kernel<<<Bdim * NCHUNK, 256, 0, stream>>>(memory, pk, beta,
                                                          sim, pvec, pmx, psum);
    epilogue_kernel<<<Bdim * NSLICE, 256, 0, stream>>>(pvec, pmx, psum, sim, beta,
                                                       read_vec, weights);
}

// Round 7
// 53.884 us; speedup vs baseline: 1.2782x; 1.1572x over previous
//
#include <hip/hip_runtime.h>
#include <math.h>

constexpr int Bdim = 32;
constexpr int Mdim = 8192;
constexpr int Idim = 256;
constexpr int ROWS_PER_BLOCK = 128;               // 4 waves x 32 rows
constexpr int ROWS_PER_WAVE = 32;                 // 4 groups of 8
constexpr int NCHUNK = Mdim / ROWS_PER_BLOCK;     // 64 chunks per b
constexpr int NSLICE = 8;                         // epilogue parallelism per b

// ---------------------------------------------------------------------------
// 1) projected_key[b,i] = tanh(sum_k key[b,k] * W[i,k] + bias[i])
//    grid = B*8; block computes 32 outputs, 8 lanes per output.
// ---------------------------------------------------------------------------
__global__ void proj_key_kernel(const float* __restrict__ key,
                                const float* __restrict__ W,
                                const float* __restrict__ bias,
                                float* __restrict__ pk) {
    int b = blockIdx.x >> 3;
    int slice = blockIdx.x & 7;
    int tid = threadIdx.x;
    int row = slice * 32 + (tid >> 3);            // output index i
    int seg = tid & 7;                            // 32-element segment of K

    const float4* w4 = (const float4*)(W + (size_t)row * Idim) + seg * 8;
    const float4* k4 = (const float4*)(key + (size_t)b * Idim) + seg * 8;
    float s = 0.f;
    #pragma unroll
    for (int k = 0; k < 8; ++k) {
        float4 wv = w4[k];
        float4 kv = k4[k];
        s += wv.x * kv.x + wv.y * kv.y + wv.z * kv.z + wv.w * kv.w;
    }
    s += __shfl_xor(s, 4, 64);                    // reduce within 8-lane group
    s += __shfl_xor(s, 2, 64);
    s += __shfl_xor(s, 1, 64);
    if (seg == 0) pk[(size_t)b * Idim + row] = tanhf(s + bias[row]);
}

// ---------------------------------------------------------------------------
// 2) FUSED single pass over memory. One wave per row, but 8 rows batched per
//    reduction step so the 6-level shfl latency chains pipeline (8-way ILP).
//    Online softmax per 8-row group: one max-tree + guarded rescale.
// ---------------------------------------------------------------------------
__global__ void fused_pass1_kernel(const float* __restrict__ memory,
                                   const float* __restrict__ pk,
                                   const float* __restrict__ beta,
                                   float* __restrict__ sim,
                                   float* __restrict__ pvec,
                                   float* __restrict__ pmx,
                                   float* __restrict__ psum) {
    int b = blockIdx.x / NCHUNK;
    int c = blockIdx.x % NCHUNK;
    int wave = threadIdx.x >> 6;
    int lane = threadIdx.x & 63;
    float bt = beta[b];

    float4 pkv = ((const float4*)(pk + (size_t)b * Idim))[lane];

    int row0 = c * ROWS_PER_BLOCK + wave * ROWS_PER_WAVE;
    const float* base = memory + ((size_t)b * Mdim + row0) * Idim;
    float* simp = sim + (size_t)b * Mdim + row0;

    float mx = -INFINITY, ssum = 0.f;
    float4 acc = make_float4(0.f, 0.f, 0.f, 0.f);
    float my_sim = 0.f;                           // lane r (<32) keeps sim of row r

    const float4* rp = (const float4*)base + lane;   // row stride = 64 float4

    for (int g = 0; g < ROWS_PER_WAVE / 8; ++g) { // 4 groups of 8 rows
        float4 m[8];
        #pragma unroll
        for (int j = 0; j < 8; ++j)
            m[j] = rp[(size_t)(g * 8 + j) * 64];  // 8 independent 1KiB loads

        float s[8];
        #pragma unroll
        for (int j = 0; j < 8; ++j) {
            float dx = pkv.x - m[j].x, dy = pkv.y - m[j].y;
            float dz = pkv.z - m[j].z, dw = pkv.w - m[j].w;
            s[j] = dx * dx + dy * dy + dz * dz + dw * dw;
        }
        // 8 interleaved butterfly reduces — independent chains pipeline
        #pragma unroll
        for (int off = 32; off; off >>= 1) {
            #pragma unroll
            for (int j = 0; j < 8; ++j) s[j] += __shfl_xor(s[j], off, 64);
        }
        if ((lane >> 3) == g) my_sim = -s[lane & 7];

        #pragma unroll
        for (int j = 0; j < 8; ++j) s[j] = -bt * s[j];   // a[j]
        float gm = fmaxf(fmaxf(fmaxf(s[0], s[1]), fmaxf(s[2], s[3])),
                         fmaxf(fmaxf(s[4], s[5]), fmaxf(s[6], s[7])));
        if (gm > mx) {                            // wave-uniform, once per group
            float sc = __expf(mx - gm);           // exp(-inf)=0 handles g=0
            ssum *= sc;
            acc.x *= sc; acc.y *= sc; acc.z *= sc; acc.w *= sc;
            mx = gm;
        }
        float ps = 0.f;
        #pragma unroll
        for (int j = 0; j < 8; ++j) {
            float p = __expf(s[j] - mx);          // 8 independent exps
            ps += p;
            acc.x = fmaf(p, m[j].x, acc.x);
            acc.y = fmaf(p, m[j].y, acc.y);
            acc.z = fmaf(p, m[j].z, acc.z);
            acc.w = fmaf(p, m[j].w, acc.w);
        }
        ssum += ps;
    }
    if (lane < 32) simp[lane] = my_sim;           // coalesced 32-row sim store

    // combine the block's 4 waves in LDS
    __shared__ float lacc[4][Idim];
    __shared__ float lmx[4], lsum[4];
    ((float4*)lacc[wave])[lane] = acc;
    if (lane == 0) { lmx[wave] = mx; lsum[wave] = ssum; }
    __syncthreads();

    float MX = fmaxf(fmaxf(lmx[0], lmx[1]), fmaxf(lmx[2], lmx[3]));
    float e0 = __expf(lmx[0] - MX), e1 = __expf(lmx[1] - MX);
    float e2 = __expf(lmx[2] - MX), e3 = __expf(lmx[3] - MX);
    int i = threadIdx.x;
    float v = lacc[0][i] * e0 + lacc[1][i] * e1 + lacc[2][i] * e2 + lacc[3][i] * e3;
    size_t pc = (size_t)b * NCHUNK + c;
    pvec[pc * Idim + i] = v;
    if (threadIdx.x == 0) {
        pmx[pc] = MX;
        psum[pc] = lsum[0] * e0 + lsum[1] * e1 + lsum[2] * e2 + lsum[3] * e3;
    }
}

// ---------------------------------------------------------------------------
// 3) Epilogue, grid = B * NSLICE blocks. Every block redundantly reduces the
//    64 chunk (mx,sum) pairs for its b; slice 0 emits read_vector; each slice
//    emits Mdim/NSLICE weights (one float4 per thread).
// ---------------------------------------------------------------------------
__global__ void epilogue_kernel(const float* __restrict__ pvec,
                                const float* __restrict__ pmx,
                                const float* __restrict__ psum,
                                const float* __restrict__ sim,
                                const float* __restrict__ beta,
                                float* __restrict__ read_vec,
                                float* __restrict__ weights) {
    int b = blockIdx.x / NSLICE;
    int slice = blockIdx.x % NSLICE;
    int tid = threadIdx.x;
    __shared__ float e[NCHUNK];
    __shared__ float MXs, sInvs;

    if (tid < NCHUNK) {                           // wave 0 handles the scalars
        float m = pmx[(size_t)b * NCHUNK + tid];
        float mm = m;
        #pragma unroll
        for (int off = 32; off; off >>= 1) mm = fmaxf(mm, __shfl_xor(mm, off, 64));
        float ec = __expf(m - mm);
        e[tid] = ec;
        float sc = psum[(size_t)b * NCHUNK + tid] * ec;
        #pragma unroll
        for (int off = 32; off; off >>= 1) sc += __shfl_xor(sc, off, 64);
        if (tid == 0) { MXs = mm; sInvs = 1.f / sc; }
    }
    __syncthreads();

    float MX = MXs, inv = sInvs;

    if (slice == 0) {                             // read_vector
        float v = 0.f;
        const float* p = pvec + (size_t)b * NCHUNK * Idim + tid;
        #pragma unroll 8
        for (int c = 0; c < NCHUNK; ++c) v += p[(size_t)c * Idim] * e[c];
        read_vec[(size_t)b * Idim + tid] = v * inv;
    }

    // weights: this slice covers Mdim/NSLICE = 1024 elems = 256 float4s
    float bt = beta[b];
    int m4 = slice * (Mdim / NSLICE / 4) + tid;
    float4 s = ((const float4*)(sim + (size_t)b * Mdim))[m4];
    float4 w;
    w.x = __expf(bt * s.x - MX) * inv;
    w.y = __expf(bt * s.y - MX) * inv;
    w.z = __expf(bt * s.z - MX) * inv;
    w.w = __expf(bt * s.w - MX) * inv;
    ((float4*)(weights + (size_t)b * Mdim))[m4] = w;
}

extern "C" void kernel_launch(void* const* d_in, const int* in_sizes, int n_in,
                              void* d_out, int out_size, void* d_ws, size_t ws_size,
                              hipStream_t stream) {
    const float* memory = (const float*)d_in[0];   // [B, M, I]
    const float* key    = (const float*)d_in[1];   // [B, I]
    const float* beta   = (const float*)d_in[2];   // [B]
    const float* W      = (const float*)d_in[3];   // [I, I]
    const float* bias   = (const float*)d_in[4];   // [I]

    float* out = (float*)d_out;
    float* weights  = out;                                     // [B, M]
    float* read_vec = out + (size_t)Bdim * Mdim;               // [B, I]
    float* sim      = read_vec + (size_t)Bdim * Idim;          // [B, M]

    float* pk   = (float*)d_ws;                                // [B, I]
    float* pvec = pk + (size_t)Bdim * Idim;                    // [B, NCHUNK, I]
    float* pmx  = pvec + (size_t)Bdim * NCHUNK * Idim;         // [B, NCHUNK]
    float* psum = pmx + (size_t)Bdim * NCHUNK;                 // [B, NCHUNK]

    proj_key_kernel<<<Bdim * 8, 256, 0, stream>>>(key, W, bias, pk);
    fused_pass1_kernel<<<Bdim * NCHUNK, 256, 0, stream>>>(memory, pk, beta,
                                                          sim, pvec, pmx, psum);
    epilogue_kernel<<<Bdim * NSLICE, 256, 0, stream>>>(pvec, pmx, psum, sim, beta,
                                                       read_vec, weights);
}